// Round 1
// baseline (361.769 us; speedup 1.0000x reference)
//
#include <hip/hip_runtime.h>
#include <math.h>

// DynamicAttention1 on MI355X — fp32 baseline, factorized softmax.
//
// Key identity: softmax over joint (s,t) of (qs[s]-qt[t])/c factorizes, so the
// marginals ws/wt (the only downstream consumers) are plain 100-wide softmaxes:
//   ws = softmax(qs/c) over s, wt = softmax(-qt/c) over t, c = sqrt(2*512) = 32.
// ctx = ([ws,wt] @ [skey; -tkey]) / sqrt(2);  out = [query,ctx] @ Wo + bo.
//
// Pipeline (all fp32, 5 launches):
//   1. q    = query @ Wq + bq                      (1024 x 512 x 512)
//   2. keys = [src;trg] @ Ws + bs                  (1600 x 2048 x 512)
//   3. ws/wt: per-(b,l) dots + 100-wide softmaxes  -> transposed [b][s][l] layout
//   4. ctx  = [ws,wt] @ [skey;-tkey] / sqrt(2)     (batched, K=200)
//   5. out  = [query,ctx] @ Wo + bo                (1024 x 1024 x 512)

// ---------------- generic 64x64 tile fp32 GEMM (BK=16, 4x4 microtile) -------

struct ASimple {
    const float* A; int K;
    __device__ __forceinline__ float4 ld(int row, int k) const {
        return *(const float4*)(A + (size_t)row * K + k);
    }
};
struct ARowSplit {           // rows < split from A1, rest from A2 (same K)
    const float* A1; const float* A2; int K; int split;
    __device__ __forceinline__ float4 ld(int row, int k) const {
        const float* p = (row < split) ? (A1 + (size_t)row * K)
                                       : (A2 + (size_t)(row - split) * K);
        return *(const float4*)(p + k);
    }
};
struct AColSplit {           // cols < K1 from A1, rest from A2 (each K1 wide)
    const float* A1; const float* A2; int K1;
    __device__ __forceinline__ float4 ld(int row, int k) const {
        const float* p = (k < K1) ? (A1 + (size_t)row * K1 + k)
                                  : (A2 + (size_t)row * K1 + (k - K1));
        return *(const float4*)p;
    }
};

template <class AF>
__device__ __forceinline__ void gemm64_body(AF af, const float* __restrict__ W,
                                            const float* __restrict__ bias,
                                            float* __restrict__ C,
                                            int M, int K, int N) {
    // stride 68 keeps float4 alignment (68*4 % 16 == 0) and kills >2-way conflicts
    __shared__ __align__(16) float As[16][68];   // transposed: As[k][m]
    __shared__ __align__(16) float Bs[16][68];   // Bs[k][n]

    const int t  = threadIdx.x;
    const int tx = t & 15, ty = t >> 4;
    const int m0 = blockIdx.y * 64, n0 = blockIdx.x * 64;
    const int arow = t >> 2, kq = (t & 3) * 4;   // A staging: 64 rows x 4 float4
    const int brow = t >> 4, nq = (t & 15) * 4;  // B staging: 16 rows x 16 float4

    float acc[4][4] = {};

    for (int k0 = 0; k0 < K; k0 += 16) {
        float4 av = make_float4(0.f, 0.f, 0.f, 0.f);
        const int r = m0 + arow;
        if (r < M) av = af.ld(r, k0 + kq);
        const float4 bv = *(const float4*)(W + (size_t)(k0 + brow) * N + n0 + nq);
        __syncthreads();                       // previous tile fully consumed
        As[kq + 0][arow] = av.x;
        As[kq + 1][arow] = av.y;
        As[kq + 2][arow] = av.z;
        As[kq + 3][arow] = av.w;
        *(float4*)&Bs[brow][nq] = bv;
        __syncthreads();
#pragma unroll
        for (int kk = 0; kk < 16; kk++) {
            float ar[4], br[4];
            *(float4*)ar = *(const float4*)&As[kk][ty * 4];
            *(float4*)br = *(const float4*)&Bs[kk][tx * 4];
#pragma unroll
            for (int i = 0; i < 4; i++)
#pragma unroll
                for (int j = 0; j < 4; j++)
                    acc[i][j] = fmaf(ar[i], br[j], acc[i][j]);
        }
    }

    float b4[4];
    *(float4*)b4 = *(const float4*)(bias + n0 + tx * 4);
#pragma unroll
    for (int i = 0; i < 4; i++) {
        const int r = m0 + ty * 4 + i;
        if (r < M) {
            float4 o = make_float4(acc[i][0] + b4[0], acc[i][1] + b4[1],
                                   acc[i][2] + b4[2], acc[i][3] + b4[3]);
            *(float4*)(C + (size_t)r * N + n0 + tx * 4) = o;
        }
    }
}

__global__ __launch_bounds__(256) void k_gemm_simple(
    const float* A, const float* W, const float* bias, float* C,
    int M, int K, int N) {
    gemm64_body(ASimple{A, K}, W, bias, C, M, K, N);
}
__global__ __launch_bounds__(256) void k_gemm_rowsplit(
    const float* A1, const float* A2, int split, const float* W,
    const float* bias, float* C, int M, int K, int N) {
    gemm64_body(ARowSplit{A1, A2, K, split}, W, bias, C, M, K, N);
}
__global__ __launch_bounds__(256) void k_gemm_colsplit(
    const float* A1, const float* A2, int K1, const float* W,
    const float* bias, float* C, int M, int K, int N) {
    gemm64_body(AColSplit{A1, A2, K1}, W, bias, C, M, K, N);
}

// ---------------- scores + factorized softmax -------------------------------
// One block per (b,l). 4 waves; each wave computes 50 of the 200 dots
// (dot(q_row, key_row), 512 wide) via 8 elems/lane + shuffle reduce.
// Then waves 0/1 do the two 100-wide softmaxes and write transposed
// wsT[b][s][l] / wtT[b][t][l] so the ctx GEMM stages coalesced.

__global__ __launch_bounds__(256) void k_scores(
    const float* __restrict__ q, const float* __restrict__ keys,
    float* __restrict__ wsT, float* __restrict__ wtT) {
    __shared__ __align__(16) float qsh[512];
    __shared__ float sc[200];

    const int t = threadIdx.x;
    const int row = blockIdx.x;          // b*128 + l
    const int b = row >> 7, l = row & 127;

    if (t < 128)
        *(float4*)&qsh[t * 4] = *(const float4*)(q + (size_t)row * 512 + t * 4);
    __syncthreads();

    const int wave = t >> 6, lane = t & 63;
    const float4* qp = (const float4*)qsh;
    const float4 qv1 = qp[lane], qv2 = qp[lane + 64];

    for (int idx = wave; idx < 200; idx += 4) {
        const int kr = (idx < 100) ? (b * 100 + idx)
                                   : (800 + b * 100 + (idx - 100));
        const float4* kp = (const float4*)(keys + (size_t)kr * 512);
        const float4 kv1 = kp[lane], kv2 = kp[lane + 64];
        float d = kv1.x * qv1.x + kv1.y * qv1.y + kv1.z * qv1.z + kv1.w * qv1.w
                + kv2.x * qv2.x + kv2.y * qv2.y + kv2.z * qv2.z + kv2.w * qv2.w;
#pragma unroll
        for (int off = 32; off > 0; off >>= 1) d += __shfl_down(d, off);
        if (lane == 0)
            sc[idx] = ((idx < 100) ? d : -d) * (1.0f / 32.0f);  // 1/sqrt(2*512)
    }
    __syncthreads();

    if (wave < 2) {
        const float* sp = sc + wave * 100;
        const bool hi = (lane + 64) < 100;
        const float v0 = sp[lane];
        const float v1 = hi ? sp[lane + 64] : -INFINITY;
        float mx = fmaxf(v0, v1);
#pragma unroll
        for (int off = 32; off > 0; off >>= 1) mx = fmaxf(mx, __shfl_xor(mx, off));
        const float e0 = __expf(v0 - mx);
        const float e1 = hi ? __expf(v1 - mx) : 0.f;
        float s = e0 + e1;
#pragma unroll
        for (int off = 32; off > 0; off >>= 1) s += __shfl_xor(s, off);
        const float inv = 1.f / s;
        float* op = (wave == 0) ? wsT : wtT;
        op[(b * 100 + lane) * 128 + l] = e0 * inv;
        if (hi) op[(b * 100 + lane + 64) * 128 + l] = e1 * inv;
    }
}

// ---------------- ctx = [ws,wt] @ [skey;-tkey] / sqrt(2) --------------------
// grid (n_tile=8, b=8); block computes 128(l) x 64(n), K=200 in chunks of 40.

__global__ __launch_bounds__(256) void k_ctx(
    const float* __restrict__ wsT, const float* __restrict__ wtT,
    const float* __restrict__ keys, float* __restrict__ ctx) {
    __shared__ __align__(16) float As[40][128];  // As[k][l]
    __shared__ __align__(16) float Bs[40][64];   // Bs[k][n]

    const int t = threadIdx.x;
    const int b = blockIdx.y;
    const int n0 = blockIdx.x * 64;
    const int tx = t & 15, ty = t >> 4;
    const float* skey = keys;
    const float* tkey = keys + (size_t)800 * 512;

    float acc[8][4] = {};

    for (int c = 0; c < 5; c++) {
        const int kbase = c * 40;
        __syncthreads();
#pragma unroll
        for (int e = 0; e < 20; e++) {
            const int idx = t + e * 256;
            const int k = idx >> 7, lidx = idx & 127;
            const int kk = kbase + k;
            As[k][lidx] = (kk < 100)
                ? wsT[(b * 100 + kk) * 128 + lidx]
                : wtT[(b * 100 + (kk - 100)) * 128 + lidx];
        }
#pragma unroll
        for (int e = 0; e < 10; e++) {
            const int idx = t + e * 256;
            const int k = idx >> 6, n = idx & 63;
            const int kk = kbase + k;
            Bs[k][n] = (kk < 100)
                ?  skey[(size_t)(b * 100 + kk) * 512 + n0 + n]
                : -tkey[(size_t)(b * 100 + (kk - 100)) * 512 + n0 + n];
        }
        __syncthreads();
#pragma unroll 8
        for (int k = 0; k < 40; k++) {
            float br[4], ar[8];
            *(float4*)br       = *(const float4*)&Bs[k][tx * 4];
            *(float4*)ar       = *(const float4*)&As[k][ty * 8];
            *(float4*)(ar + 4) = *(const float4*)&As[k][ty * 8 + 4];
#pragma unroll
            for (int i = 0; i < 8; i++)
#pragma unroll
                for (int j = 0; j < 4; j++)
                    acc[i][j] = fmaf(ar[i], br[j], acc[i][j]);
        }
    }

    const float s2 = 0.70710678118654752f;  // 1/sqrt(2)
#pragma unroll
    for (int i = 0; i < 8; i++) {
        const int r = b * 128 + ty * 8 + i;
        float4 o = make_float4(acc[i][0] * s2, acc[i][1] * s2,
                               acc[i][2] * s2, acc[i][3] * s2);
        *(float4*)(ctx + (size_t)r * 512 + n0 + tx * 4) = o;
    }
}

// ---------------- launch ----------------------------------------------------

extern "C" void kernel_launch(void* const* d_in, const int* in_sizes, int n_in,
                              void* d_out, int out_size, void* d_ws, size_t ws_size,
                              hipStream_t stream) {
    const float* query = (const float*)d_in[0];
    const float* src   = (const float*)d_in[1];
    const float* trg   = (const float*)d_in[2];
    const float* Wq    = (const float*)d_in[3];
    const float* bq    = (const float*)d_in[4];
    const float* Ws    = (const float*)d_in[5];
    const float* bs    = (const float*)d_in[6];
    const float* Wo    = (const float*)d_in[7];
    const float* bo    = (const float*)d_in[8];
    float* out = (float*)d_out;

    // workspace layout (floats): total ~2.07M floats = 8.3 MB
    float* ws_f = (float*)d_ws;
    float* q    = ws_f;                       // 1024*512
    float* keys = q    + 1024 * 512;          // 1600*512 (skey rows 0..799, tkey 800..1599)
    float* wsT  = keys + 1600 * 512;          // 8*100*128, [b][s][l]
    float* wtT  = wsT  + 8 * 100 * 128;       // 8*100*128
    float* ctx  = wtT  + 8 * 100 * 128;       // 1024*512

    // 1. q = query @ Wq + bq
    k_gemm_simple<<<dim3(8, 16), 256, 0, stream>>>(query, Wq, bq, q, 1024, 512, 512);
    // 2. keys = [src; trg] @ Ws + bs   (shared weights -> one fused GEMM, M=1600)
    k_gemm_rowsplit<<<dim3(8, 25), 256, 0, stream>>>(src, trg, 800, Ws, bs, keys,
                                                     1600, 2048, 512);
    // 3. factorized softmax marginals
    k_scores<<<dim3(1024), 256, 0, stream>>>(q, keys, wsT, wtT);
    // 4. ctx
    k_ctx<<<dim3(8, 8), 256, 0, stream>>>(wsT, wtT, keys, ctx);
    // 5. out = [query, ctx] @ Wo + bo
    k_gemm_colsplit<<<dim3(8, 16), 256, 0, stream>>>(query, ctx, 512, Wo, bo, out,
                                                     1024, 1024, 512);
}

// Round 2
// 220.517 us; speedup vs baseline: 1.6405x; 1.6405x over previous
//
#include <hip/hip_runtime.h>
#include <math.h>

// DynamicAttention1 — round 2: bf16 MFMA for the three dense GEMMs.
//
// Pipeline (8 launches, single stream):
//   1. k_cast      : query,src,trg fp32 -> bf16 (query also scattered into the
//                    out-GEMM A buffer columns 0..511)
//   2. k_transcast : Wq,Ws,Wo fp32 [K][N] -> bf16 [N][K] (gemm_bt B operand)
//   3. k_mfma_gemm : q    = query @ Wq + bq   (1024 x 512 x 512)  -> fp32
//   4. k_mfma_gemm : keys = [src;trg] @ Ws+bs (1600 x 2048 x 512) -> fp32
//   5. k_scores    : factorized softmax marginals (unchanged, fp32)
//   6. k_ctx       : ctx = [ws,wt]@[skey;-tkey]/sqrt2 -> bf16 into A_out[:,512:]
//   7. k_mfma_gemm : out  = [query,ctx] @ Wo + bo (1024 x 1024 x 512) -> d_out

typedef __attribute__((ext_vector_type(8))) short s16x8;
typedef __attribute__((ext_vector_type(4))) float f32x4;

__device__ __forceinline__ unsigned short f2bf(float f) {
    unsigned int u = __float_as_uint(f);
    return (unsigned short)((u + 0x7fffu + ((u >> 16) & 1u)) >> 16);  // RNE
}

// ---------------- activation cast: fp32 -> bf16 -----------------------------
// groups of 4 floats; query 131072 groups, src 409600, trg 409600 -> 3712 blocks
__global__ __launch_bounds__(256) void k_cast(
    const float* __restrict__ query, const float* __restrict__ src,
    const float* __restrict__ trg, unsigned short* __restrict__ qbf,
    unsigned short* __restrict__ aout, unsigned short* __restrict__ abf) {
    const int idx = blockIdx.x * 256 + threadIdx.x;
    if (idx < 131072) {
        float4 v = *(const float4*)(query + (size_t)idx * 4);
        ushort4 o = make_ushort4(f2bf(v.x), f2bf(v.y), f2bf(v.z), f2bf(v.w));
        *(ushort4*)(qbf + (size_t)idx * 4) = o;
        const int flat = idx * 4, m = flat >> 9, c = flat & 511;
        *(ushort4*)(aout + (size_t)m * 1024 + c) = o;          // A_out left half
    } else if (idx < 131072 + 409600) {
        const int i = idx - 131072;
        float4 v = *(const float4*)(src + (size_t)i * 4);
        *(ushort4*)(abf + (size_t)i * 4) =
            make_ushort4(f2bf(v.x), f2bf(v.y), f2bf(v.z), f2bf(v.w));
    } else {
        const int i = idx - 540672;
        float4 v = *(const float4*)(trg + (size_t)i * 4);
        *(ushort4*)(abf + 1638400 + (size_t)i * 4) =
            make_ushort4(f2bf(v.x), f2bf(v.y), f2bf(v.z), f2bf(v.w));
    }
}

// ---------------- weight transpose-cast: [K][N=512] fp32 -> [N][K] bf16 -----
// 32x32 tiles; Wq 256 tiles (K=512), Ws 1024 (K=2048), Wo 512 (K=1024) = 1792
__global__ __launch_bounds__(256) void k_transcast(
    const float* __restrict__ Wq, const float* __restrict__ Ws,
    const float* __restrict__ Wo, unsigned short* __restrict__ WqT,
    unsigned short* __restrict__ WsT, unsigned short* __restrict__ WoT) {
    const int id = blockIdx.x;
    const float* W; unsigned short* O; int K, tk, tn;
    if (id < 256)       { W = Wq; O = WqT; K = 512;  tk = id >> 4;          tn = id & 15; }
    else if (id < 1280) { W = Ws; O = WsT; K = 2048; tk = (id - 256) >> 4;  tn = (id - 256) & 15; }
    else                { W = Wo; O = WoT; K = 1024; tk = (id - 1280) >> 4; tn = (id - 1280) & 15; }
    __shared__ float tile[32][33];
    const int t = threadIdx.x, row = t >> 3, c4 = (t & 7) * 4;
    float4 v = *(const float4*)(W + (size_t)(tk * 32 + row) * 512 + tn * 32 + c4);
    tile[row][c4 + 0] = v.x; tile[row][c4 + 1] = v.y;
    tile[row][c4 + 2] = v.z; tile[row][c4 + 3] = v.w;
    __syncthreads();
    ushort4 o = make_ushort4(f2bf(tile[c4 + 0][row]), f2bf(tile[c4 + 1][row]),
                             f2bf(tile[c4 + 2][row]), f2bf(tile[c4 + 3][row]));
    *(ushort4*)(O + (size_t)(tn * 32 + row) * K + tk * 32 + c4) = o;
}

// ---------------- bf16 MFMA GEMM: C = A @ BT^T + bias -----------------------
// A [M][K] bf16, BT [N][K] bf16, C [M][N] fp32. 64x64 tile, BK=64, 256 thr,
// 4 waves 2x2, each wave 32x32 (2x2 mfma_f32_16x16x32_bf16 frags).
// LDS rows padded to 72 bf16 (144 B): row r shifts banks by 4r -> 2-way max.
__global__ __launch_bounds__(256) void k_mfma_gemm(
    const unsigned short* __restrict__ A, const unsigned short* __restrict__ BT,
    const float* __restrict__ bias, float* __restrict__ C,
    int M, int K, int N) {
    __shared__ __align__(16) unsigned short As[64 * 72];
    __shared__ __align__(16) unsigned short Bs[64 * 72];
    const int t = threadIdx.x;
    const int m0 = blockIdx.y * 64, n0 = blockIdx.x * 64;
    const int lane = t & 63, wid = t >> 6;
    const int wm = (wid & 1) * 32, wn = (wid >> 1) * 32;
    const int lr = lane & 15, lq = lane >> 4;

    f32x4 acc[2][2] = {};

    for (int kt = 0; kt < K; kt += 64) {
        __syncthreads();                       // previous tile fully consumed
#pragma unroll
        for (int i = 0; i < 2; i++) {
            const int idx = i * 256 + t, r = idx >> 3, c = idx & 7;
            *(s16x8*)&As[r * 72 + c * 8] =
                *(const s16x8*)(A + (size_t)(m0 + r) * K + kt + c * 8);
            *(s16x8*)&Bs[r * 72 + c * 8] =
                *(const s16x8*)(BT + (size_t)(n0 + r) * K + kt + c * 8);
        }
        __syncthreads();
#pragma unroll
        for (int s = 0; s < 2; s++) {
            s16x8 a0 = *(const s16x8*)&As[(wm + lr) * 72      + s * 32 + lq * 8];
            s16x8 a1 = *(const s16x8*)&As[(wm + 16 + lr) * 72 + s * 32 + lq * 8];
            s16x8 b0 = *(const s16x8*)&Bs[(wn + lr) * 72      + s * 32 + lq * 8];
            s16x8 b1 = *(const s16x8*)&Bs[(wn + 16 + lr) * 72 + s * 32 + lq * 8];
            acc[0][0] = __builtin_amdgcn_mfma_f32_16x16x32_bf16(a0, b0, acc[0][0], 0, 0, 0);
            acc[0][1] = __builtin_amdgcn_mfma_f32_16x16x32_bf16(a0, b1, acc[0][1], 0, 0, 0);
            acc[1][0] = __builtin_amdgcn_mfma_f32_16x16x32_bf16(a1, b0, acc[1][0], 0, 0, 0);
            acc[1][1] = __builtin_amdgcn_mfma_f32_16x16x32_bf16(a1, b1, acc[1][1], 0, 0, 0);
        }
    }

#pragma unroll
    for (int i = 0; i < 2; i++)
#pragma unroll
        for (int j = 0; j < 2; j++) {
            const int col = n0 + wn + j * 16 + lr;      // C/D: col = lane&15
            const int row = m0 + wm + i * 16 + lq * 4;  //      row = quad*4+reg
            const float bv = bias[col];
#pragma unroll
            for (int r = 0; r < 4; r++)
                C[(size_t)(row + r) * N + col] = acc[i][j][r] + bv;
        }
}

// ---------------- scores + factorized softmax (unchanged, fp32) -------------
__global__ __launch_bounds__(256) void k_scores(
    const float* __restrict__ q, const float* __restrict__ keys,
    float* __restrict__ wsT, float* __restrict__ wtT) {
    __shared__ __align__(16) float qsh[512];
    __shared__ float sc[200];

    const int t = threadIdx.x;
    const int row = blockIdx.x;          // b*128 + l
    const int b = row >> 7, l = row & 127;

    if (t < 128)
        *(float4*)&qsh[t * 4] = *(const float4*)(q + (size_t)row * 512 + t * 4);
    __syncthreads();

    const int wave = t >> 6, lane = t & 63;
    const float4* qp = (const float4*)qsh;
    const float4 qv1 = qp[lane], qv2 = qp[lane + 64];

    for (int idx = wave; idx < 200; idx += 4) {
        const int kr = (idx < 100) ? (b * 100 + idx)
                                   : (800 + b * 100 + (idx - 100));
        const float4* kp = (const float4*)(keys + (size_t)kr * 512);
        const float4 kv1 = kp[lane], kv2 = kp[lane + 64];
        float d = kv1.x * qv1.x + kv1.y * qv1.y + kv1.z * qv1.z + kv1.w * qv1.w
                + kv2.x * qv2.x + kv2.y * qv2.y + kv2.z * qv2.z + kv2.w * qv2.w;
#pragma unroll
        for (int off = 32; off > 0; off >>= 1) d += __shfl_down(d, off);
        if (lane == 0)
            sc[idx] = ((idx < 100) ? d : -d) * (1.0f / 32.0f);  // 1/sqrt(2*512)
    }
    __syncthreads();

    if (wave < 2) {
        const float* sp = sc + wave * 100;
        const bool hi = (lane + 64) < 100;
        const float v0 = sp[lane];
        const float v1 = hi ? sp[lane + 64] : -INFINITY;
        float mx = fmaxf(v0, v1);
#pragma unroll
        for (int off = 32; off > 0; off >>= 1) mx = fmaxf(mx, __shfl_xor(mx, off));
        const float e0 = __expf(v0 - mx);
        const float e1 = hi ? __expf(v1 - mx) : 0.f;
        float s = e0 + e1;
#pragma unroll
        for (int off = 32; off > 0; off >>= 1) s += __shfl_xor(s, off);
        const float inv = 1.f / s;
        float* op = (wave == 0) ? wsT : wtT;
        op[(b * 100 + lane) * 128 + l] = e0 * inv;
        if (hi) op[(b * 100 + lane + 64) * 128 + l] = e1 * inv;
    }
}

// ---------------- ctx -> bf16 into A_out columns 512..1023 ------------------
// grid (8 n-tiles, 8 b, 2 l-halves) = 128 blocks; 64(l) x 64(n), K=200.
__global__ __launch_bounds__(256) void k_ctx(
    const float* __restrict__ wsT, const float* __restrict__ wtT,
    const float* __restrict__ keys, unsigned short* __restrict__ aout) {
    __shared__ float As[40][64];   // As[k][l]
    __shared__ float Bs[40][64];   // Bs[k][n]

    const int t = threadIdx.x;
    const int b = blockIdx.y;
    const int n0 = blockIdx.x * 64;
    const int l0 = blockIdx.z * 64;
    const int tx = t & 15, ty = t >> 4;

    float acc[4][4] = {};

    for (int c5 = 0; c5 < 5; c5++) {
        const int kbase = c5 * 40;
        __syncthreads();
#pragma unroll
        for (int e = 0; e < 10; e++) {
            const int idx = t + e * 256;
            const int k = idx >> 6, j = idx & 63;
            const int kk = kbase + k;
            As[k][j] = (kk < 100) ? wsT[(b * 100 + kk) * 128 + l0 + j]
                                  : wtT[(b * 100 + (kk - 100)) * 128 + l0 + j];
            Bs[k][j] = (kk < 100)
                ?  keys[(size_t)(b * 100 + kk) * 512 + n0 + j]
                : -keys[(size_t)(800 + b * 100 + (kk - 100)) * 512 + n0 + j];
        }
        __syncthreads();
#pragma unroll 8
        for (int k = 0; k < 40; k++) {
            float ar[4], br[4];
            *(float4*)ar = *(const float4*)&As[k][ty * 4];
            *(float4*)br = *(const float4*)&Bs[k][tx * 4];
#pragma unroll
            for (int i = 0; i < 4; i++)
#pragma unroll
                for (int j = 0; j < 4; j++)
                    acc[i][j] = fmaf(ar[i], br[j], acc[i][j]);
        }
    }

    const float s2 = 0.70710678118654752f;  // 1/sqrt(2)
#pragma unroll
    for (int i = 0; i < 4; i++) {
        const int m = b * 128 + l0 + ty * 4 + i;
        ushort4 o = make_ushort4(f2bf(acc[i][0] * s2), f2bf(acc[i][1] * s2),
                                 f2bf(acc[i][2] * s2), f2bf(acc[i][3] * s2));
        *(ushort4*)(aout + (size_t)m * 1024 + 512 + n0 + tx * 4) = o;
    }
}

// ---------------- launch ----------------------------------------------------

extern "C" void kernel_launch(void* const* d_in, const int* in_sizes, int n_in,
                              void* d_out, int out_size, void* d_ws, size_t ws_size,
                              hipStream_t stream) {
    const float* query = (const float*)d_in[0];
    const float* src   = (const float*)d_in[1];
    const float* trg   = (const float*)d_in[2];
    const float* Wq    = (const float*)d_in[3];
    const float* bq    = (const float*)d_in[4];
    const float* Ws    = (const float*)d_in[5];
    const float* bs    = (const float*)d_in[6];
    const float* Wo    = (const float*)d_in[7];
    const float* bo    = (const float*)d_in[8];
    float* out = (float*)d_out;

    // workspace: fp32 region then bf16 region (all 16B-aligned), ~19.6 MB
    float* q    = (float*)d_ws;               // 1024*512
    float* keys = q    + 524288;              // 1600*512
    float* wsT  = keys + 819200;              // 8*100*128
    float* wtT  = wsT  + 102400;
    unsigned short* qbf = (unsigned short*)(wtT + 102400);
    unsigned short* abf = qbf + 524288;       // [src;trg] 1600x2048
    unsigned short* aout= abf + 3276800;      // [query,ctx] 1024x1024
    unsigned short* wqt = aout + 1048576;     // WqT 512x512
    unsigned short* wst = wqt  + 262144;      // WsT 512x2048
    unsigned short* wot = wst  + 1048576;     // WoT 512x1024

    k_cast<<<3712, 256, 0, stream>>>(query, src, trg, qbf, aout, abf);
    k_transcast<<<1792, 256, 0, stream>>>(Wq, Ws, Wo, wqt, wst, wot);
    k_mfma_gemm<<<dim3(8, 16), 256, 0, stream>>>(qbf, wqt, bq, q, 1024, 512, 512);
    k_mfma_gemm<<<dim3(8, 25), 256, 0, stream>>>(abf, wst, bs, keys, 1600, 2048, 512);
    k_scores<<<1024, 256, 0, stream>>>(q, keys, wsT, wtT);
    k_ctx<<<dim3(8, 8, 2), 256, 0, stream>>>(wsT, wtT, keys, aout);
    k_mfma_gemm<<<dim3(8, 16), 256, 0, stream>>>(aout, wot, bo, out, 1024, 1024, 512);
}

// Round 3
// 158.826 us; speedup vs baseline: 2.2778x; 1.3884x over previous
//
#include <hip/hip_runtime.h>
#include <math.h>

// DynamicAttention1 — round 3: occupancy attack.
// R2 counters: keys GEMM 48.8us at Occ 7.6%, MfmaUtil 2.3% -> latency-bound
// (200 blocks = 1 wave/SIMD, 32-iter serial K chain). Fixes:
//   * keys: split-K x4 (8-iter chains) + fp32 unsafeAtomicAdd, 800 blocks
//   * q/out: 32x64 tiles -> 256 blocks each, direct write
//   * q merged into keys launch (1056 blocks total)
//   * cast+transcast+bias-init merged into k_prep
//   * k_ctx: 256 blocks
// 5 launches: prep -> stageB(q+keys) -> scores -> ctx -> out

typedef __attribute__((ext_vector_type(8))) short s16x8;
typedef __attribute__((ext_vector_type(4))) float f32x4;

__device__ __forceinline__ unsigned short f2bf(float f) {
    unsigned int u = __float_as_uint(f);
    return (unsigned short)((u + 0x7fffu + ((u >> 16) & 1u)) >> 16);  // RNE
}

// ---------------- prep: casts + weight transposes + keys bias init ----------
__global__ __launch_bounds__(256) void k_prep(
    const float* __restrict__ query, const float* __restrict__ src,
    const float* __restrict__ trg, const float* __restrict__ Wq,
    const float* __restrict__ Ws, const float* __restrict__ Wo,
    const float* __restrict__ bs, unsigned short* __restrict__ qbf,
    unsigned short* __restrict__ aout, unsigned short* __restrict__ abf,
    unsigned short* __restrict__ WqT, unsigned short* __restrict__ WsT,
    unsigned short* __restrict__ WoT, float* __restrict__ keys) {
    __shared__ float tile[32][33];
    const int bid = blockIdx.x, t = threadIdx.x;

    if (bid < 3712) {                       // activation casts (float4 groups)
        const int idx = bid * 256 + t;
        if (idx < 131072) {
            float4 v = *(const float4*)(query + (size_t)idx * 4);
            ushort4 o = make_ushort4(f2bf(v.x), f2bf(v.y), f2bf(v.z), f2bf(v.w));
            *(ushort4*)(qbf + (size_t)idx * 4) = o;
            const int flat = idx * 4, m = flat >> 9, c = flat & 511;
            *(ushort4*)(aout + (size_t)m * 1024 + c) = o;   // A_out left half
        } else if (idx < 540672) {
            const int i = idx - 131072;
            float4 v = *(const float4*)(src + (size_t)i * 4);
            *(ushort4*)(abf + (size_t)i * 4) =
                make_ushort4(f2bf(v.x), f2bf(v.y), f2bf(v.z), f2bf(v.w));
        } else {
            const int i = idx - 540672;
            float4 v = *(const float4*)(trg + (size_t)i * 4);
            *(ushort4*)(abf + 1638400 + (size_t)i * 4) =
                make_ushort4(f2bf(v.x), f2bf(v.y), f2bf(v.z), f2bf(v.w));
        }
    } else if (bid < 5504) {                // weight transpose-cast, 32x32 tiles
        const int id = bid - 3712;
        const float* W; unsigned short* O; int K, tk, tn;
        if (id < 256)       { W = Wq; O = WqT; K = 512;  tk = id >> 4;          tn = id & 15; }
        else if (id < 1280) { W = Ws; O = WsT; K = 2048; tk = (id - 256) >> 4;  tn = (id - 256) & 15; }
        else                { W = Wo; O = WoT; K = 1024; tk = (id - 1280) >> 4; tn = (id - 1280) & 15; }
        const int row = t >> 3, c4 = (t & 7) * 4;
        float4 v = *(const float4*)(W + (size_t)(tk * 32 + row) * 512 + tn * 32 + c4);
        tile[row][c4 + 0] = v.x; tile[row][c4 + 1] = v.y;
        tile[row][c4 + 2] = v.z; tile[row][c4 + 3] = v.w;
        __syncthreads();
        ushort4 o = make_ushort4(f2bf(tile[c4 + 0][row]), f2bf(tile[c4 + 1][row]),
                                 f2bf(tile[c4 + 2][row]), f2bf(tile[c4 + 3][row]));
        *(ushort4*)(O + (size_t)(tn * 32 + row) * K + tk * 32 + c4) = o;
    } else {                                // keys = broadcast bias (split-K acc base)
        const int i = (bid - 5504) * 256 + t;
        const int f = i * 4;
        *(float4*)(keys + f) = *(const float4*)(bs + (f & 511));
    }
}

// ---------------- MFMA GEMM bodies ------------------------------------------
// A [M][K] bf16, BT [N][K] bf16. LDS rows padded to 72 bf16 (144 B).

// 64x64 tile, 4 waves 2x2, split-K partial accumulated via fp32 atomics.
__device__ __forceinline__ void gemm64_atomic(
    const unsigned short* __restrict__ A, const unsigned short* __restrict__ BT,
    float* __restrict__ C, int m0, int n0, int K, int N, int kbase, int kiters,
    unsigned short* As, unsigned short* Bs) {
    const int t = threadIdx.x;
    const int lane = t & 63, wid = t >> 6;
    const int wm = (wid & 1) * 32, wn = (wid >> 1) * 32;
    const int lr = lane & 15, lq = lane >> 4;

    f32x4 acc[2][2] = {};
    for (int it = 0; it < kiters; it++) {
        const int kt = kbase + it * 64;
        __syncthreads();
#pragma unroll
        for (int i = 0; i < 2; i++) {
            const int idx = i * 256 + t, r = idx >> 3, c = idx & 7;
            *(s16x8*)&As[r * 72 + c * 8] =
                *(const s16x8*)(A + (size_t)(m0 + r) * K + kt + c * 8);
            *(s16x8*)&Bs[r * 72 + c * 8] =
                *(const s16x8*)(BT + (size_t)(n0 + r) * K + kt + c * 8);
        }
        __syncthreads();
#pragma unroll
        for (int s = 0; s < 2; s++) {
            s16x8 a0 = *(const s16x8*)&As[(wm + lr) * 72      + s * 32 + lq * 8];
            s16x8 a1 = *(const s16x8*)&As[(wm + 16 + lr) * 72 + s * 32 + lq * 8];
            s16x8 b0 = *(const s16x8*)&Bs[(wn + lr) * 72      + s * 32 + lq * 8];
            s16x8 b1 = *(const s16x8*)&Bs[(wn + 16 + lr) * 72 + s * 32 + lq * 8];
            acc[0][0] = __builtin_amdgcn_mfma_f32_16x16x32_bf16(a0, b0, acc[0][0], 0, 0, 0);
            acc[0][1] = __builtin_amdgcn_mfma_f32_16x16x32_bf16(a0, b1, acc[0][1], 0, 0, 0);
            acc[1][0] = __builtin_amdgcn_mfma_f32_16x16x32_bf16(a1, b0, acc[1][0], 0, 0, 0);
            acc[1][1] = __builtin_amdgcn_mfma_f32_16x16x32_bf16(a1, b1, acc[1][1], 0, 0, 0);
        }
    }
#pragma unroll
    for (int i = 0; i < 2; i++)
#pragma unroll
        for (int j = 0; j < 2; j++) {
            const int col = n0 + wn + j * 16 + lr;      // C/D: col=lane&15
            const int row = m0 + wm + i * 16 + lq * 4;  //      row=quad*4+reg
#pragma unroll
            for (int r = 0; r < 4; r++)
                unsafeAtomicAdd(&C[(size_t)(row + r) * N + col], acc[i][j][r]);
        }
}

// 32x64 tile, 4 waves (16x32 each), direct write + bias.
__device__ __forceinline__ void gemm32(
    const unsigned short* __restrict__ A, const unsigned short* __restrict__ BT,
    const float* __restrict__ bias, float* __restrict__ C,
    int m0, int n0, int K, int N, int kiters,
    unsigned short* As, unsigned short* Bs) {
    const int t = threadIdx.x;
    const int lane = t & 63, wid = t >> 6;
    const int wm = (wid & 1) * 16, wn = (wid >> 1) * 32;
    const int lr = lane & 15, lq = lane >> 4;

    f32x4 acc[2] = {};
    for (int it = 0; it < kiters; it++) {
        const int kt = it * 64;
        __syncthreads();
        {   // A: 32 rows
            const int r = t >> 3, c = t & 7;
            *(s16x8*)&As[r * 72 + c * 8] =
                *(const s16x8*)(A + (size_t)(m0 + r) * K + kt + c * 8);
        }
#pragma unroll
        for (int i = 0; i < 2; i++) {   // B: 64 rows
            const int idx = i * 256 + t, r = idx >> 3, c = idx & 7;
            *(s16x8*)&Bs[r * 72 + c * 8] =
                *(const s16x8*)(BT + (size_t)(n0 + r) * K + kt + c * 8);
        }
        __syncthreads();
#pragma unroll
        for (int s = 0; s < 2; s++) {
            s16x8 a0 = *(const s16x8*)&As[(wm + lr) * 72      + s * 32 + lq * 8];
            s16x8 b0 = *(const s16x8*)&Bs[(wn + lr) * 72      + s * 32 + lq * 8];
            s16x8 b1 = *(const s16x8*)&Bs[(wn + 16 + lr) * 72 + s * 32 + lq * 8];
            acc[0] = __builtin_amdgcn_mfma_f32_16x16x32_bf16(a0, b0, acc[0], 0, 0, 0);
            acc[1] = __builtin_amdgcn_mfma_f32_16x16x32_bf16(a0, b1, acc[1], 0, 0, 0);
        }
    }
#pragma unroll
    for (int j = 0; j < 2; j++) {
        const int col = n0 + wn + j * 16 + lr;
        const int row = m0 + wm + lq * 4;
        const float bv = bias[col];
#pragma unroll
        for (int r = 0; r < 4; r++)
            C[(size_t)(row + r) * N + col] = acc[j][r] + bv;
    }
}

// ---------------- stage B: q GEMM + keys GEMM in one grid -------------------
// blocks [0,800): keys split-K  (c = b/200, 200 tiles of 64x64, K-chunk 512)
// blocks [800,1056): q          (32x64 tiles, K=512)
__global__ __launch_bounds__(256) void k_stageB(
    const unsigned short* __restrict__ qbf, const unsigned short* __restrict__ abf,
    const unsigned short* __restrict__ WqT, const unsigned short* __restrict__ WsT,
    const float* __restrict__ bq, float* __restrict__ q, float* __restrict__ keys) {
    __shared__ __align__(16) unsigned short As[64 * 72];
    __shared__ __align__(16) unsigned short Bs[64 * 72];
    const int bid = blockIdx.x;
    if (bid < 800) {
        const int c = bid / 200, rem = bid % 200;
        const int mt = rem >> 3, nt = rem & 7;
        gemm64_atomic(abf, WsT, keys, mt * 64, nt * 64, 2048, 512, c * 512, 8, As, Bs);
    } else {
        const int r = bid - 800;
        const int mt = r >> 3, nt = r & 7;
        gemm32(qbf, WqT, bq, q, mt * 32, nt * 64, 512, 512, 8, As, Bs);
    }
}

// ---------------- out = [query,ctx] @ Wo + bo -------------------------------
__global__ __launch_bounds__(256) void k_out(
    const unsigned short* __restrict__ aout, const unsigned short* __restrict__ WoT,
    const float* __restrict__ bo, float* __restrict__ out) {
    __shared__ __align__(16) unsigned short As[64 * 72];
    __shared__ __align__(16) unsigned short Bs[64 * 72];
    gemm32(aout, WoT, bo, out, blockIdx.y * 32, blockIdx.x * 64, 1024, 512, 16, As, Bs);
}

// ---------------- scores + factorized softmax (fp32) ------------------------
__global__ __launch_bounds__(256) void k_scores(
    const float* __restrict__ q, const float* __restrict__ keys,
    float* __restrict__ wsT, float* __restrict__ wtT) {
    __shared__ __align__(16) float qsh[512];
    __shared__ float sc[200];

    const int t = threadIdx.x;
    const int row = blockIdx.x;          // b*128 + l
    const int b = row >> 7, l = row & 127;

    if (t < 128)
        *(float4*)&qsh[t * 4] = *(const float4*)(q + (size_t)row * 512 + t * 4);
    __syncthreads();

    const int wave = t >> 6, lane = t & 63;
    const float4* qp = (const float4*)qsh;
    const float4 qv1 = qp[lane], qv2 = qp[lane + 64];

    for (int idx = wave; idx < 200; idx += 4) {
        const int kr = (idx < 100) ? (b * 100 + idx)
                                   : (800 + b * 100 + (idx - 100));
        const float4* kp = (const float4*)(keys + (size_t)kr * 512);
        const float4 kv1 = kp[lane], kv2 = kp[lane + 64];
        float d = kv1.x * qv1.x + kv1.y * qv1.y + kv1.z * qv1.z + kv1.w * qv1.w
                + kv2.x * qv2.x + kv2.y * qv2.y + kv2.z * qv2.z + kv2.w * qv2.w;
#pragma unroll
        for (int off = 32; off > 0; off >>= 1) d += __shfl_down(d, off);
        if (lane == 0)
            sc[idx] = ((idx < 100) ? d : -d) * (1.0f / 32.0f);  // 1/sqrt(2*512)
    }
    __syncthreads();

    if (wave < 2) {
        const float* sp = sc + wave * 100;
        const bool hi = (lane + 64) < 100;
        const float v0 = sp[lane];
        const float v1 = hi ? sp[lane + 64] : -INFINITY;
        float mx = fmaxf(v0, v1);
#pragma unroll
        for (int off = 32; off > 0; off >>= 1) mx = fmaxf(mx, __shfl_xor(mx, off));
        const float e0 = __expf(v0 - mx);
        const float e1 = hi ? __expf(v1 - mx) : 0.f;
        float s = e0 + e1;
#pragma unroll
        for (int off = 32; off > 0; off >>= 1) s += __shfl_xor(s, off);
        const float inv = 1.f / s;
        float* op = (wave == 0) ? wsT : wtT;
        op[(b * 100 + lane) * 128 + l] = e0 * inv;
        if (hi) op[(b * 100 + lane + 64) * 128 + l] = e1 * inv;
    }
}

// ---------------- ctx -> bf16 into A_out cols 512..1023 ---------------------
// grid (16 n-tiles of 32, 8 b, 2 l-halves) = 256 blocks; 64(l) x 32(n), K=200.
__global__ __launch_bounds__(256) void k_ctx(
    const float* __restrict__ wsT, const float* __restrict__ wtT,
    const float* __restrict__ keys, unsigned short* __restrict__ aout) {
    __shared__ float As[40][64];   // As[k][l]
    __shared__ float Bs[40][32];   // Bs[k][n]

    const int t = threadIdx.x;
    const int b = blockIdx.y;
    const int n0 = blockIdx.x * 32;
    const int l0 = blockIdx.z * 64;
    const int tx = t & 7, ty = t >> 3;   // tx: n/4, ty: l/2

    float acc[2][4] = {};

    for (int c5 = 0; c5 < 5; c5++) {
        const int kbase = c5 * 40;
        __syncthreads();
#pragma unroll
        for (int e = 0; e < 10; e++) {
            const int idx = t + e * 256;
            const int k = idx >> 6, j = idx & 63;
            const int kk = kbase + k;
            As[k][j] = (kk < 100) ? wsT[(b * 100 + kk) * 128 + l0 + j]
                                  : wtT[(b * 100 + (kk - 100)) * 128 + l0 + j];
        }
#pragma unroll
        for (int e = 0; e < 5; e++) {
            const int idx = t + e * 256;
            const int k = idx >> 5, j = idx & 31;
            const int kk = kbase + k;
            Bs[k][j] = (kk < 100)
                ?  keys[(size_t)(b * 100 + kk) * 512 + n0 + j]
                : -keys[(size_t)(800 + b * 100 + (kk - 100)) * 512 + n0 + j];
        }
        __syncthreads();
#pragma unroll 8
        for (int k = 0; k < 40; k++) {
            float ar0 = As[k][ty * 2], ar1 = As[k][ty * 2 + 1];
            float br[4];
            *(float4*)br = *(const float4*)&Bs[k][tx * 4];
#pragma unroll
            for (int j = 0; j < 4; j++) {
                acc[0][j] = fmaf(ar0, br[j], acc[0][j]);
                acc[1][j] = fmaf(ar1, br[j], acc[1][j]);
            }
        }
    }

    const float s2 = 0.70710678118654752f;  // 1/sqrt(2)
#pragma unroll
    for (int i = 0; i < 2; i++) {
        const int m = b * 128 + l0 + ty * 2 + i;
        ushort4 o = make_ushort4(f2bf(acc[i][0] * s2), f2bf(acc[i][1] * s2),
                                 f2bf(acc[i][2] * s2), f2bf(acc[i][3] * s2));
        *(ushort4*)(aout + (size_t)m * 1024 + 512 + n0 + tx * 4) = o;
    }
}

// ---------------- launch ----------------------------------------------------

extern "C" void kernel_launch(void* const* d_in, const int* in_sizes, int n_in,
                              void* d_out, int out_size, void* d_ws, size_t ws_size,
                              hipStream_t stream) {
    const float* query = (const float*)d_in[0];
    const float* src   = (const float*)d_in[1];
    const float* trg   = (const float*)d_in[2];
    const float* Wq    = (const float*)d_in[3];
    const float* bq    = (const float*)d_in[4];
    const float* Ws    = (const float*)d_in[5];
    const float* bs    = (const float*)d_in[6];
    const float* Wo    = (const float*)d_in[7];
    const float* bo    = (const float*)d_in[8];
    float* out = (float*)d_out;

    float* q    = (float*)d_ws;               // 1024*512
    float* keys = q    + 524288;              // 1600*512
    float* wsT  = keys + 819200;              // 8*100*128
    float* wtT  = wsT  + 102400;
    unsigned short* qbf = (unsigned short*)(wtT + 102400);
    unsigned short* abf = qbf + 524288;       // [src;trg] 1600x2048
    unsigned short* aout= abf + 3276800;      // [query,ctx] 1024x1024
    unsigned short* wqt = aout + 1048576;     // WqT 512x512
    unsigned short* wst = wqt  + 262144;      // WsT 512x2048
    unsigned short* wot = wst  + 1048576;     // WoT 512x1024

    k_prep<<<6304, 256, 0, stream>>>(query, src, trg, Wq, Ws, Wo, bs,
                                     qbf, aout, abf, wqt, wst, wot, keys);
    k_stageB<<<1056, 256, 0, stream>>>(qbf, abf, wqt, wst, bq, q, keys);
    k_scores<<<1024, 256, 0, stream>>>(q, keys, wsT, wtT);
    k_ctx<<<dim3(16, 8, 2), 256, 0, stream>>>(wsT, wtT, keys, aout);
    k_out<<<dim3(8, 32), 256, 0, stream>>>(aout, wot, bo, out);
}